// Round 7
// baseline (112.667 us; speedup 1.0000x reference)
//
#include <hip/hip_runtime.h>
#include <hip/hip_bf16.h>

typedef __attribute__((ext_vector_type(8))) short short8v;
typedef __attribute__((ext_vector_type(4))) float f32x4;

#define DEVFN __device__ __forceinline__

DEVFN unsigned short f2bf(float x) {
  __hip_bfloat16 h = __float2bfloat16(x);
  return *reinterpret_cast<unsigned short*>(&h);
}

DEVFN float bf2f(unsigned short u) {
  unsigned int x = ((unsigned int)u) << 16;
  float f;
  __builtin_memcpy(&f, &x, 4);
  return f;
}

DEVFN void gload16(const void* g, void* l) {
  __builtin_amdgcn_global_load_lds(
      (const __attribute__((address_space(1))) void*)g,
      (__attribute__((address_space(3))) void*)l, 16, 0, 0);
}

// Weight transpose-casts + q_start only (input casts fused into the GEMMs).
__global__ __launch_bounds__(256) void prep(
    const float* __restrict__ Wk, const float* __restrict__ Wv,
    const float* __restrict__ Wq, const float* __restrict__ Wo,
    const float* __restrict__ Wg,
    unsigned short* __restrict__ Btkv, unsigned short* __restrict__ Btq,
    unsigned short* __restrict__ Bto, unsigned short* __restrict__ Btg,
    const int* __restrict__ q_idx, int* __restrict__ q_start, int Q, int E) {
  const int b = blockIdx.x, t = threadIdx.x;
  if (b < 256) {  // Wk/Wv/Wq/Wo transpose-cast: 64 blocks each
    const int wi = b >> 6, bb = b & 63;
    const float* W = (wi == 0) ? Wk : (wi == 1) ? Wv : (wi == 2) ? Wq : Wo;
    unsigned short* O = (wi == 0) ? Btkv : (wi == 1) ? (Btkv + 65536)
                     : (wi == 2) ? Btq : Bto;
    for (int id = bb * 256 + t; id < 65536; id += 64 * 256) {
      const int n = id >> 8, k = id & 255;
      O[id] = f2bf(W[k * 256 + n]);
    }
  } else if (b < 272) {  // Wg [64][256] -> Btg [256][64]
    for (int id = (b - 256) * 256 + t; id < 16384; id += 16 * 256) {
      const int n = id >> 6, k = id & 63;
      Btg[id] = f2bf(Wg[k * 256 + n]);
    }
  } else {  // q_start: lower_bound over sorted q_idx
    const int q = (b - 272) * 256 + t;
    if (q <= Q) {
      int lo = 0, hi = E;
      while (lo < hi) { int mid = (lo + hi) >> 1; if (q_idx[mid] < q) lo = mid + 1; else hi = mid; }
      q_start[q] = lo;
    }
  }
}

// C = A @ Bt^T. A: fp32 [M][K] reg-staged (global->reg->cvt once->swizzled
// ds_write_b128 as bf16) or bf16 [M][K] via global_load_lds. Bt: bf16 [NB][K]
// via global_load_lds. 128x128 tile, BK=32, 4 waves (2x2), 4x4 frags of
// mfma_f32_16x16x32_bf16. Both LDS tiles are bf16 [128][32], chunk-swizzle
// cs = c ^ ((row>>1)&3) (0-conflict, r3-verified). Double-buffered, ONE
// barrier per K-iter: stage(t+1) -> compute(t) -> vmcnt(0)+lgkm(0) -> barrier.
// OUT_MODE: 0 = fp32, 1 = bf16, at row*ldc+col.
template <bool A_F32, int OUT_MODE, bool HAS_BIAS>
__global__ __launch_bounds__(256) void gemm_mfma(
    const void* __restrict__ Av, const unsigned short* __restrict__ Bt,
    void* __restrict__ Cv, const float* __restrict__ bias, int K, int ldc) {
  __shared__ unsigned short As[2][128 * 32];  // 8 KB each
  __shared__ unsigned short Bs[2][128 * 32];  // 8 KB each

  const int t = threadIdx.x;
  const int wv = t >> 6, l = t & 63;
  const int wr = wv >> 1, wc = wv & 1;
  const int lr = l & 15, lk = l >> 4;

  // XCD-bijective swizzle (all launches have nwg % 8 == 0)
  const int gx = gridDim.x;
  const int nwg = gx * gridDim.y;
  const int orig = blockIdx.y * gx + blockIdx.x;
  const int cpx = nwg >> 3;
  const int swz = (orig & 7) * cpx + (orig >> 3);
  const int n0 = (swz % gx) * 128;
  const int m0 = (swz / gx) * 128;

  f32x4 acc[4][4];
#pragma unroll
  for (int m = 0; m < 4; ++m)
#pragma unroll
    for (int n = 0; n < 4; ++n) acc[m][n] = (f32x4){0.f, 0.f, 0.f, 0.f};

  const int wbase = (t & ~63) * 16;  // wave-uniform LDS byte base for gload16

  // A reg-stage assignment: thread t -> row = t>>1, 64 B (16 fp32) starting
  // at chunk ac0 = (t&1)*2. Consecutive lanes cover consecutive 64 B -> fully
  // coalesced 128 B per row.
  const int arow = t >> 1;
  const int ac0 = (t & 1) * 2;

  float4 av0, av1, av2, av3;
  auto loadA = [&](int k0) {
    const float* Ap = (const float*)Av + (size_t)(m0 + arow) * K + k0 + ac0 * 8;
    av0 = ((const float4*)Ap)[0];
    av1 = ((const float4*)Ap)[1];
    av2 = ((const float4*)Ap)[2];
    av3 = ((const float4*)Ap)[3];
  };
  auto writeA = [&](int buf) {
    unsigned short u[16];
    u[0] = f2bf(av0.x); u[1] = f2bf(av0.y); u[2] = f2bf(av0.z); u[3] = f2bf(av0.w);
    u[4] = f2bf(av1.x); u[5] = f2bf(av1.y); u[6] = f2bf(av1.z); u[7] = f2bf(av1.w);
    u[8] = f2bf(av2.x); u[9] = f2bf(av2.y); u[10] = f2bf(av2.z); u[11] = f2bf(av2.w);
    u[12] = f2bf(av3.x); u[13] = f2bf(av3.y); u[14] = f2bf(av3.z); u[15] = f2bf(av3.w);
    const int cs0 = ac0 ^ ((arow >> 1) & 3);
    const int cs1 = (ac0 + 1) ^ ((arow >> 1) & 3);
    *(short8v*)&As[buf][arow * 32 + cs0 * 8] = *(short8v*)&u[0];
    *(short8v*)&As[buf][arow * 32 + cs1 * 8] = *(short8v*)&u[8];
  };
  auto stageA_lds = [&](int buf, int k0) {
    const unsigned short* Ab = (const unsigned short*)Av;
#pragma unroll
    for (int s = 0; s < 2; ++s) {
      const int cidx = s * 256 + t;
      const int row = cidx >> 2, c = cidx & 3;
      const int cs = c ^ ((row >> 1) & 3);
      gload16(Ab + (size_t)(m0 + row) * K + k0 + cs * 8,
              (char*)&As[buf][0] + (size_t)s * 4096 + wbase);
    }
  };
  auto stageB = [&](int buf, int k0) {
#pragma unroll
    for (int s = 0; s < 2; ++s) {
      const int cidx = s * 256 + t;
      const int row = cidx >> 2, c = cidx & 3;
      const int cs = c ^ ((row >> 1) & 3);
      gload16(Bt + (size_t)(n0 + row) * K + k0 + cs * 8,
              (char*)&Bs[buf][0] + (size_t)s * 4096 + wbase);
    }
  };

  auto compute = [&](int buf) {
    short8v a[4], b[4];
#pragma unroll
    for (int m = 0; m < 4; ++m) {
      const int row = wr * 64 + m * 16 + lr;
      const int cs = lk ^ ((row >> 1) & 3);
      a[m] = *(const short8v*)&As[buf][row * 32 + cs * 8];
    }
#pragma unroll
    for (int n = 0; n < 4; ++n) {
      const int row = wc * 64 + n * 16 + lr;
      const int cs = lk ^ ((row >> 1) & 3);
      b[n] = *(const short8v*)&Bs[buf][row * 32 + cs * 8];
    }
#pragma unroll
    for (int m = 0; m < 4; ++m)
#pragma unroll
      for (int n = 0; n < 4; ++n)
        acc[m][n] = __builtin_amdgcn_mfma_f32_16x16x32_bf16(a[m], b[n], acc[m][n], 0, 0, 0);
  };

  const int nt = K >> 5;
  // prologue: stage tile 0
  if (A_F32) {
    loadA(0);
    stageB(0, 0);
    writeA(0);  // compiler inserts the vmcnt wait for av* before first use
  } else {
    stageA_lds(0, 0);
    stageB(0, 0);
  }
  asm volatile("s_waitcnt vmcnt(0) lgkmcnt(0)" ::: "memory");
  __builtin_amdgcn_s_barrier();
  __builtin_amdgcn_sched_barrier(0);

  for (int tt = 0; tt < nt - 1; ++tt) {
    const int cur = tt & 1, nxt = cur ^ 1;
    const int k1 = (tt + 1) * 32;
    if (A_F32) {
      loadA(k1);          // issue early: hidden under compute
      stageB(nxt, k1);
      compute(cur);
      writeA(nxt);        // different buffer: no barrier needed before write
    } else {
      stageA_lds(nxt, k1);
      stageB(nxt, k1);
      compute(cur);
    }
    // nxt fully staged (loads issued ~a compute-phase ago) + LDS ops drained
    asm volatile("s_waitcnt vmcnt(0) lgkmcnt(0)" ::: "memory");
    __builtin_amdgcn_s_barrier();
    __builtin_amdgcn_sched_barrier(0);
  }
  compute((nt - 1) & 1);

  // epilogue: C/D layout col = lane&15, row = (lane>>4)*4 + reg (m89-verified)
#pragma unroll
  for (int m = 0; m < 4; ++m)
#pragma unroll
    for (int n = 0; n < 4; ++n) {
      const f32x4 v = acc[m][n];
      const int col = n0 + wc * 64 + n * 16 + lr;
      const int rbase = m0 + wr * 64 + m * 16 + lk * 4;
      float bv = 0.f;
      if (HAS_BIAS) bv = bias[col];
#pragma unroll
      for (int r = 0; r < 4; ++r) {
        const float val = v[r] + bv;
        if (OUT_MODE == 0) {
          ((float*)Cv)[(size_t)(rbase + r) * ldc + col] = val;
        } else {
          ((unsigned short*)Cv)[(size_t)(rbase + r) * ldc + col] = f2bf(val);
        }
      }
    }
}

// One block (256 thr) per query. 8 edge streams per block: stream =
// wave*2 + (lane>=32), 32 lanes per edge, 8 dims per lane (uint4 = 8 bf16).
// KV planar: row = 512 bf16 = K(256)|V(256). s_idx staged in LDS; rolling
// depth-1 KV prefetch per stream. No online max (exact; scores bounded) ->
// stream partials merge by summation.
__global__ __launch_bounds__(256) void edge_attn(
    const int* __restrict__ s_idx, const int* __restrict__ q_start,
    const uint4* __restrict__ KV4, const unsigned short* __restrict__ Qf,
    const unsigned short* __restrict__ Gf, unsigned short* __restrict__ out_pre,
    const float* __restrict__ log_tau) {
  const int q = blockIdx.x;
  const int t = threadIdx.x;
  const int w = t >> 6;
  const int lane = t & 63;
  const int stream = w * 2 + (lane >> 5);  // 0..7
  const int sl = lane & 31;                // lane within edge
  const int start = q_start[q], end = q_start[q + 1];

  const float tau = __expf(log_tau[0]);
  const float rs = 1.0f / (5.656854249492381f * tau);  // 1/(sqrt(32)*tau)

  float qv[8];
  {
    uint4 qw = *(const uint4*)(Qf + (size_t)q * 256 + sl * 8);
    const unsigned int ws_[4] = {qw.x, qw.y, qw.z, qw.w};
#pragma unroll
    for (int j = 0; j < 4; ++j) {
      qv[2 * j]     = bf2f((unsigned short)(ws_[j] & 0xffffu)) * rs;
      qv[2 * j + 1] = bf2f((unsigned short)(ws_[j] >> 16)) * rs;
    }
  }

  float o[8];
#pragma unroll
  for (int j = 0; j < 8; ++j) o[j] = 0.f;
  float lsum_p = 0.f;

  __shared__ int sseg[1024];

  for (int cb = start; cb < end; cb += 1024) {
    const int nb = min(1024, end - cb);
    __syncthreads();
    for (int jj = t; jj < nb; jj += 256) sseg[jj] = s_idx[cb + jj];
    __syncthreads();

    int j = stream;
    uint4 kc, vc;
    if (j < nb) {
      const uint4* bp = KV4 + (size_t)sseg[j] * 64;
      kc = bp[sl];
      vc = bp[32 + sl];
    }
    while (j < nb) {
      const int jn = j + 8;
      const bool more = jn < nb;
      uint4 kcn, vcn;
      if (more) {
        const uint4* bpn = KV4 + (size_t)sseg[jn] * 64;
        kcn = bpn[sl];
        vcn = bpn[32 + sl];
      }
      const unsigned int kw[4] = {kc.x, kc.y, kc.z, kc.w};
      float p = 0.f;
#pragma unroll
      for (int jj = 0; jj < 4; ++jj) {
        p = fmaf(qv[2 * jj], bf2f((unsigned short)(kw[jj] & 0xffffu)), p);
        p = fmaf(qv[2 * jj + 1], bf2f((unsigned short)(kw[jj] >> 16)), p);
      }
      p += __shfl_xor(p, 1);
      p += __shfl_xor(p, 2);   // full 32-dim head dot (4-lane group)
      const float ew = __expf(p);
      lsum_p += ew;
      const unsigned int vw[4] = {vc.x, vc.y, vc.z, vc.w};
#pragma unroll
      for (int jj = 0; jj < 4; ++jj) {
        o[2 * jj]     = fmaf(ew, bf2f((unsigned short)(vw[jj] & 0xffffu)), o[2 * jj]);
        o[2 * jj + 1] = fmaf(ew, bf2f((unsigned short)(vw[jj] >> 16)), o[2 * jj + 1]);
      }
      j = jn;
      kc = kcn;
      vc = vcn;
    }
  }

  __shared__ float o_sh[8][256];
  __shared__ float l_sh[8][8];
  *(float4*)&o_sh[stream][sl * 8]     = (float4){o[0], o[1], o[2], o[3]};
  *(float4*)&o_sh[stream][sl * 8 + 4] = (float4){o[4], o[5], o[6], o[7]};
  if ((sl & 3) == 0) l_sh[stream][sl >> 2] = lsum_p;
  __syncthreads();

  float osum = 0.f, lsum = 0.f;
  const int h = t >> 5;
#pragma unroll
  for (int s = 0; s < 8; ++s) {
    osum += o_sh[s][t];
    lsum += l_sh[s][h];
  }
  const float inv = 1.0f / fmaxf(lsum, 1e-8f);
  float res = 0.f;
  if (end > start) res = osum * inv + (lsum * inv) * bf2f(Gf[(size_t)q * 256 + t]);
  out_pre[(size_t)q * 256 + t] = f2bf(res);
}

extern "C" void kernel_launch(void* const* d_in, const int* in_sizes, int n_in,
                              void* d_out, int out_size, void* d_ws, size_t ws_size,
                              hipStream_t stream) {
  const float* query   = (const float*)d_in[0];
  const float* support = (const float*)d_in[1];
  const float* geo     = (const float*)d_in[2];
  const int*   q_idx   = (const int*)d_in[3];
  const int*   s_idx   = (const int*)d_in[4];
  const float* Wq      = (const float*)d_in[6];
  const float* Wk      = (const float*)d_in[7];
  const float* Wv      = (const float*)d_in[8];
  const float* Wg      = (const float*)d_in[9];
  const float* Wo      = (const float*)d_in[10];
  const float* bo      = (const float*)d_in[11];
  const float* log_tau = (const float*)d_in[12];

  const int D = 256;
  const int Q = in_sizes[0] / D;   // 8192
  const int N = in_sizes[1] / D;   // 65536
  const int E = in_sizes[3];       // 262144

  unsigned short* ws = (unsigned short*)d_ws;
  unsigned short* KV   = ws;                       // [N][512] bf16 planar K|V
  unsigned short* Qf   = KV   + (size_t)N * 512;   // bf16 [Q][256]
  unsigned short* Gf   = Qf   + (size_t)Q * 256;   // bf16 [Q][256]
  unsigned short* Opre = Gf   + (size_t)Q * 256;   // bf16 [Q][256]
  unsigned short* Btkv = Opre + (size_t)Q * 256;   // [512][256] = [Wk^T; Wv^T]
  unsigned short* Btq  = Btkv + 512 * 256;         // [256][256]
  unsigned short* Btg  = Btq  + 256 * 256;         // [256][64]
  unsigned short* Bto  = Btg  + 256 * 64;          // [256][256]
  int* q_start = (int*)(Bto + 256 * 256);          // [Q+1]

  dim3 blk(256);

  prep<<<dim3(305), blk, 0, stream>>>(Wk, Wv, Wq, Wo, Wg,
                                      Btkv, Btq, Bto, Btg, q_idx, q_start, Q, E);

  // KV projection (fp32 A reg-staged to bf16 LDS), planar K|V out
  gemm_mfma<true, 1, false><<<dim3(4, N / 128), blk, 0, stream>>>(
      support, Btkv, (void*)KV, nullptr, D, 512);
  gemm_mfma<true, 1, false><<<dim3(2, Q / 128), blk, 0, stream>>>(
      query, Btq, (void*)Qf, nullptr, D, D);
  gemm_mfma<true, 1, false><<<dim3(2, Q / 128), blk, 0, stream>>>(
      geo, Btg, (void*)Gf, nullptr, 64, D);

  edge_attn<<<dim3(Q), blk, 0, stream>>>(s_idx, q_start, (const uint4*)KV,
                                         Qf, Gf, Opre, log_tau);

  gemm_mfma<false, 0, true><<<dim3(2, Q / 128), blk, 0, stream>>>(
      Opre, Bto, d_out, bo, D, D);
}